// Round 4
// baseline (3050.766 us; speedup 1.0000x reference)
//
#include <hip/hip_runtime.h>
#include <hip/hip_bf16.h>

#define BATCHN 64
#define SEQ    2048
#define HID    64
#define NF     32
#define DIN    96      // NF + HID
#define G7     448     // 7 * HID
#define CH     33      // time + 32 marks

using bf16 = __hip_bfloat16;

__device__ __forceinline__ float b2f(bf16 v) { return __bfloat162float(v); }

// Inputs are float32 per the reference (JAX fp32). Runtime-verified:
// flag==1 -> fp32, flag==0 -> bf16 (robust either way). flag==nullptr -> fp32.
__device__ __forceinline__ float ldin(const void* p, size_t i, bool f32) {
    return f32 ? ((const float*)p)[i] : b2f(((const bf16*)p)[i]);
}

// Conservative IEEE math until fully green.
__device__ __forceinline__ float sigmoid_f(float x) { return 1.0f / (1.0f + expf(-x)); }
__device__ __forceinline__ float tanh_f(float x)    { return tanhf(x); }
__device__ __forceinline__ float softplus_f(float x) {
    return fmaxf(x, 0.0f) + log1pf(expf(-fabsf(x)));
}

// Event times are a cumsum of U(0.01,1) gaps: under the CORRECT dtype view they
// are strictly increasing with bounded gaps; under the wrong view they're random
// (P[monotone over 64] ~ 1/64!).
__global__ void detect_dtype(const void* batch, int* flag) {
    if (threadIdx.x != 0 || blockIdx.x != 0) return;
    const float* bf = (const float*)batch;
    bool mono = true;
    float prev = bf[0];
    if (!(prev > 0.004f && prev < 1.3f)) mono = false;
    for (int t = 1; t < 64 && mono; ++t) {
        float cur = bf[(size_t)t * CH];
        if (!(cur > prev && (cur - prev) < 1.3f)) mono = false;
        prev = cur;
    }
    *flag = mono ? 1 : 0;
}

// One block per batch element; 448 threads = one per z column (7 gates x 64).
// Three barriers per step: every cross-wave LDS write/read pair has its own barrier.
__global__ __launch_bounds__(G7) void ctlstm_rec(
    const void* __restrict__ batch, const void* __restrict__ W_rec,
    const void* __restrict__ b_rec, float* __restrict__ out,
    float* __restrict__ h_ws, int use_ws, const int* __restrict__ flag)
{
    const bool f32 = flag ? (*flag != 0) : true;
    const int tid = threadIdx.x;
    const int b   = blockIdx.x;
    const size_t bT = (size_t)b * SEQ;

    float* out_o  = out;
    float* out_c  = out + (size_t)BATCHN * SEQ * HID;
    float* out_cb = out + 2 * (size_t)BATCHN * SEQ * HID;
    float* out_dl = out + 3 * (size_t)BATCHN * SEQ * HID;

    __shared__ __align__(16) float s_in[DIN];   // [0..31]=x_t, [32..95]=h_{t-1}
    __shared__ float s_act[G7];
    __shared__ float s_times[SEQ];

    // Per-thread register copy of W_rec column `tid` (96 fp32 regs).
    float wcol[DIN];
#pragma unroll
    for (int k = 0; k < DIN; ++k) wcol[k] = ldin(W_rec, (size_t)k * G7 + tid, f32);
    const float bias = ldin(b_rec, tid, f32);

    // Preload this batch row's event times into LDS.
    for (int i = tid; i < SEQ; i += G7)
        s_times[i] = ldin(batch, (bT + i) * CH, f32);

    if (tid >= NF && tid < DIN) s_in[tid] = 0.0f;   // h0 = 0
    float c_decay = 0.0f, c_bar = 0.0f;             // state lives in wave0 lanes

    float xpref = 0.0f;
    if (tid < NF) xpref = ldin(batch, bT * CH + 1 + tid, f32);
    __syncthreads();

    const int gate = tid >> 6;      // 0:i 1:f 2:g 3:o 4:ibar 5:fbar 6:delta
    const int lane = tid & 63;

    for (int t = 0; t < SEQ; ++t) {
        // ---- Phase A: commit x_t (h_{t-1} was written in Phase C, sealed by B3)
        if (tid < NF) s_in[tid] = xpref;
        __syncthreads();    // B1: s_in fully visible

        // ---- Phase B: z = bias + dot(s_in, wcol); broadcast float4 LDS reads
        const float4* sv = (const float4*)s_in;
        float a0 = 0.f, a1 = 0.f, a2 = 0.f, a3 = 0.f;
#pragma unroll
        for (int k4 = 0; k4 < DIN / 4; ++k4) {
            float4 v = sv[k4];
            a0 = fmaf(v.x, wcol[4 * k4 + 0], a0);
            a1 = fmaf(v.y, wcol[4 * k4 + 1], a1);
            a2 = fmaf(v.z, wcol[4 * k4 + 2], a2);
            a3 = fmaf(v.w, wcol[4 * k4 + 3], a3);
        }
        const float z = bias + ((a0 + a1) + (a2 + a3));

        float act;
        if (gate == 2)      act = tanh_f(z);      // g
        else if (gate == 6) act = softplus_f(z);  // delta
        else                act = sigmoid_f(z);   // i, f, o, ibar, fbar
        s_act[tid] = act;

        const size_t oidx = (bT + t) * HID + lane;
        if (gate == 3) out_o[oidx]  = act;
        if (gate == 6) out_dl[oidx] = act;
        __syncthreads();    // B2: all 448 activations visible

        // ---- Phase C: wave0 does the elementwise state update
        if (tid < HID) {
            const float ig = s_act[tid];
            const float fg = s_act[HID + tid];
            const float gg = s_act[2 * HID + tid];
            const float og = s_act[3 * HID + tid];
            const float ib = s_act[4 * HID + tid];
            const float fb = s_act[5 * HID + tid];
            const float dl = s_act[6 * HID + tid];
            const float c  = fg * c_decay + ig * gg;
            const float cb = fb * c_bar + ib * gg;
            float dt = (t + 1 < SEQ) ? (s_times[t + 1] - s_times[t]) : 0.0f;
            dt = fmaxf(dt, 0.0f);
            const float cd = cb + (c - cb) * expf(-dl * dt);
            const float h  = og * tanh_f(cd);
            c_decay = cd;
            c_bar   = cb;
            s_in[NF + tid] = h;
            const size_t idx = (bT + t) * HID + tid;
            out_c[idx]  = c;
            out_cb[idx] = cb;
            if (use_ws) h_ws[idx] = h;
        }
        // Prefetch x_{t+1}; s_in[0..31] is only re-touched by these same threads
        // at the next Phase A, which is beyond B3.
        if (tid < NF && t + 1 < SEQ)
            xpref = ldin(batch, (bT + t + 1) * CH + 1 + tid, f32);
        __syncthreads();    // B3: Phase C LDS writes sealed before next Phase A/B
    }
}

// Intensity head from fp32 h in workspace: softplus(h @ W_int + b_int).
__global__ __launch_bounds__(256) void intensity_ws(
    const float* __restrict__ h_ws, const void* __restrict__ W_int,
    const void* __restrict__ b_int, float* __restrict__ out_int,
    const int* __restrict__ flag)
{
    const bool f32 = flag ? (*flag != 0) : true;
    __shared__ float s_w[HID * NF];
    __shared__ float s_b[NF];
    const int tx = threadIdx.x;          // 0..31 (output feature)
    const int ty = threadIdx.y;          // 0..7  (row within block)
    const int lt = ty * 32 + tx;
    for (int k = lt; k < HID * NF; k += 256) s_w[k] = ldin(W_int, k, f32);
    if (lt < NF) s_b[lt] = ldin(b_int, lt, f32);
    __syncthreads();

    const int b = blockIdx.y;
    const int t = blockIdx.x * 8 + ty;
    if (t >= SEQ - 1) return;
    const float* hr = h_ws + ((size_t)b * SEQ + t) * HID;
    float acc = s_b[tx];
#pragma unroll
    for (int k = 0; k < HID; ++k) acc = fmaf(hr[k], s_w[k * NF + tx], acc);
    out_int[((size_t)b * (SEQ - 1) + t) * NF + tx] = softplus_f(acc);
}

// Fallback (ws too small): recompute h from fp32 outputs (o, c, cbar, delta) + dt.
__global__ __launch_bounds__(256) void intensity_rec(
    const void* __restrict__ batch, const float* __restrict__ out,
    const void* __restrict__ W_int, const void* __restrict__ b_int,
    float* __restrict__ out_int, const int* __restrict__ flag)
{
    const bool f32 = flag ? (*flag != 0) : true;
    __shared__ float s_w[HID * NF];
    __shared__ float s_b[NF];
    __shared__ float s_h[8][HID];
    const int tx = threadIdx.x, ty = threadIdx.y;
    const int lt = ty * 32 + tx;
    for (int k = lt; k < HID * NF; k += 256) s_w[k] = ldin(W_int, k, f32);
    if (lt < NF) s_b[lt] = ldin(b_int, lt, f32);

    const int b  = blockIdx.y;
    const int t0 = blockIdx.x * 8;
    const float* out_o  = out;
    const float* out_c  = out + (size_t)BATCHN * SEQ * HID;
    const float* out_cb = out + 2 * (size_t)BATCHN * SEQ * HID;
    const float* out_dl = out + 3 * (size_t)BATCHN * SEQ * HID;

#pragma unroll
    for (int r = 0; r < 2; ++r) {
        const int flat = lt + r * 256;   // 0..511
        const int row  = flat >> 6;
        const int k    = flat & 63;
        const int t    = t0 + row;
        if (t < SEQ - 1) {
            const size_t idx = ((size_t)b * SEQ + t) * HID + k;
            const float og = out_o[idx];
            const float c  = out_c[idx];
            const float cb = out_cb[idx];
            const float dl = out_dl[idx];
            const float t_a = ldin(batch, ((size_t)b * SEQ + t) * CH, f32);
            const float t_b = ldin(batch, ((size_t)b * SEQ + t + 1) * CH, f32);
            const float dt = fmaxf(t_b - t_a, 0.0f);
            const float cd = cb + (c - cb) * expf(-dl * dt);
            s_h[row][k] = og * tanh_f(cd);
        }
    }
    __syncthreads();
    const int t = t0 + ty;
    if (t >= SEQ - 1) return;
    float acc = s_b[tx];
#pragma unroll
    for (int k = 0; k < HID; ++k) acc = fmaf(s_h[ty][k], s_w[k * NF + tx], acc);
    out_int[((size_t)b * (SEQ - 1) + t) * NF + tx] = softplus_f(acc);
}

extern "C" void kernel_launch(void* const* d_in, const int* in_sizes, int n_in,
                              void* d_out, int out_size, void* d_ws, size_t ws_size,
                              hipStream_t stream) {
    const void* batch = d_in[0];
    const void* W_rec = d_in[1];
    const void* b_rec = d_in[2];
    const void* W_int = d_in[3];
    const void* b_int = d_in[4];
    float* out = (float*)d_out;

    // ws layout: [0,256) dtype flag; [256, 256+h_bytes) fp32 h buffer.
    const size_t h_bytes = (size_t)BATCHN * SEQ * HID * sizeof(float);
    int* flag = (ws_size >= 4) ? (int*)d_ws : nullptr;
    const int use_ws = (ws_size >= 256 + h_bytes) ? 1 : 0;  // launch-constant
    float* h_ws = (float*)((char*)d_ws + 256);

    if (flag) detect_dtype<<<1, 64, 0, stream>>>(batch, flag);

    ctlstm_rec<<<BATCHN, G7, 0, stream>>>(batch, W_rec, b_rec, out, h_ws, use_ws, flag);

    float* out_int = out + 4 * (size_t)BATCHN * SEQ * HID;
    if (use_ws)
        intensity_ws<<<dim3((SEQ - 1 + 7) / 8, BATCHN), dim3(32, 8), 0, stream>>>(
            h_ws, W_int, b_int, out_int, flag);
    else
        intensity_rec<<<dim3((SEQ - 1 + 7) / 8, BATCHN), dim3(32, 8), 0, stream>>>(
            batch, out, W_int, b_int, out_int, flag);
}

// Round 5
// 2393.940 us; speedup vs baseline: 1.2744x; 1.2744x over previous
//
#include <hip/hip_runtime.h>
#include <hip/hip_bf16.h>

#define BATCHN 64
#define SEQ    2048
#define HID    64
#define NF     32
#define DIN    96      // NF + HID
#define G7     448     // 7 * HID
#define CH     33      // time + 32 marks

using bf16 = __hip_bfloat16;

__device__ __forceinline__ float b2f(bf16 v) { return __bfloat162float(v); }

// Inputs are float32 (verified R4). flag==1 -> fp32, flag==0 -> bf16.
__device__ __forceinline__ float ldin(const void* p, size_t i, bool f32) {
    return f32 ? ((const float*)p)[i] : b2f(((const bf16*)p)[i]);
}

// Fast math: v_exp/v_rcp based, saturation-safe (exp->inf => rcp->0), NaN-free.
__device__ __forceinline__ float fast_rcp(float x) { return __builtin_amdgcn_rcpf(x); }
__device__ __forceinline__ float sigmoid_f(float x) {
    return fast_rcp(1.0f + __expf(-x));
}
__device__ __forceinline__ float tanh_f(float x) {
    float e = __expf(2.0f * x);                 // x<<0 -> 0 => -1 ; x>>0 -> inf => 1
    return 1.0f - 2.0f * fast_rcp(e + 1.0f);
}
__device__ __forceinline__ float softplus_f(float x) {
    float e = __expf(-fabsf(x));                // (0,1]
    return fmaxf(x, 0.0f) + __logf(1.0f + e);
}

// Event times are a cumsum of U(0.01,1) gaps: monotone with bounded gaps only
// under the correct dtype view.
__global__ void detect_dtype(const void* batch, int* flag) {
    if (threadIdx.x != 0 || blockIdx.x != 0) return;
    const float* bf = (const float*)batch;
    bool mono = true;
    float prev = bf[0];
    if (!(prev > 0.004f && prev < 1.3f)) mono = false;
    for (int t = 1; t < 16 && mono; ++t) {
        float cur = bf[(size_t)t * CH];
        if (!(cur > prev && (cur - prev) < 1.3f)) mono = false;
        prev = cur;
    }
    *flag = mono ? 1 : 0;
}

// One block per batch element; 448 threads = one per z column (7 gates x 64).
// Two barriers per step (B3 proved redundant: B1(t+1) seals Phase-C writes,
// B2(t) seals Phase-B writes; all cross-wave pairs separated).
// min-waves=2 => 256-VGPR budget so wcol[96] stays in registers (R4 spilled at 72).
__global__ __launch_bounds__(G7, 2) void ctlstm_rec(
    const void* __restrict__ batch, const void* __restrict__ W_rec,
    const void* __restrict__ b_rec, float* __restrict__ out,
    float* __restrict__ h_ws, int use_ws, const int* __restrict__ flag)
{
    const bool f32 = flag ? (*flag != 0) : true;
    const int tid = threadIdx.x;
    const int b   = blockIdx.x;
    const size_t bT = (size_t)b * SEQ;

    float* out_o  = out;
    float* out_c  = out + (size_t)BATCHN * SEQ * HID;
    float* out_cb = out + 2 * (size_t)BATCHN * SEQ * HID;
    float* out_dl = out + 3 * (size_t)BATCHN * SEQ * HID;

    __shared__ __align__(16) float s_in[DIN];   // [0..31]=x_t, [32..95]=h_{t-1}
    __shared__ float s_act[G7];
    __shared__ float s_times[SEQ];

    // Per-thread register copy of W_rec column `tid` (96 fp32 regs).
    float wcol[DIN];
#pragma unroll
    for (int k = 0; k < DIN; ++k) wcol[k] = ldin(W_rec, (size_t)k * G7 + tid, f32);
    const float bias = ldin(b_rec, tid, f32);

    // Preload this batch row's event times into LDS.
    for (int i = tid; i < SEQ; i += G7)
        s_times[i] = ldin(batch, (bT + i) * CH, f32);

    if (tid >= NF && tid < DIN) s_in[tid] = 0.0f;   // h0 = 0
    float c_decay = 0.0f, c_bar = 0.0f;             // state lives in wave0 lanes

    float xpref = 0.0f;
    if (tid < NF) xpref = ldin(batch, bT * CH + 1 + tid, f32);
    __syncthreads();

    const int gate = tid >> 6;      // 0:i 1:f 2:g 3:o 4:ibar 5:fbar 6:delta
    const int lane = tid & 63;

    for (int t = 0; t < SEQ; ++t) {
        // ---- Phase A: commit x_t (h_{t-1} Phase-C writes sealed by this barrier)
        if (tid < NF) s_in[tid] = xpref;
        __syncthreads();    // B1: s_in fully visible

        // ---- Phase B: z = bias + dot(s_in, wcol); broadcast float4 LDS reads
        const float4* sv = (const float4*)s_in;
        float a0 = 0.f, a1 = 0.f, a2 = 0.f, a3 = 0.f;
#pragma unroll
        for (int k4 = 0; k4 < DIN / 4; ++k4) {
            float4 v = sv[k4];
            a0 = fmaf(v.x, wcol[4 * k4 + 0], a0);
            a1 = fmaf(v.y, wcol[4 * k4 + 1], a1);
            a2 = fmaf(v.z, wcol[4 * k4 + 2], a2);
            a3 = fmaf(v.w, wcol[4 * k4 + 3], a3);
        }
        const float z = bias + ((a0 + a1) + (a2 + a3));

        float act;
        if (gate == 2)      act = tanh_f(z);      // g
        else if (gate == 6) act = softplus_f(z);  // delta
        else                act = sigmoid_f(z);   // i, f, o, ibar, fbar
        s_act[tid] = act;

        const size_t oidx = (bT + t) * HID + lane;
        if (gate == 3) out_o[oidx]  = act;
        if (gate == 6) out_dl[oidx] = act;
        __syncthreads();    // B2: all 448 activations visible

        // ---- Phase C: wave0 does the elementwise state update
        if (tid < HID) {
            const float ig = s_act[tid];
            const float fg = s_act[HID + tid];
            const float gg = s_act[2 * HID + tid];
            const float og = s_act[3 * HID + tid];
            const float ib = s_act[4 * HID + tid];
            const float fb = s_act[5 * HID + tid];
            const float dl = s_act[6 * HID + tid];
            const float c  = fg * c_decay + ig * gg;
            const float cb = fb * c_bar + ib * gg;
            float dt = (t + 1 < SEQ) ? (s_times[t + 1] - s_times[t]) : 0.0f;
            dt = fmaxf(dt, 0.0f);
            const float cd = cb + (c - cb) * __expf(-dl * dt);
            const float h  = og * tanh_f(cd);
            c_decay = cd;
            c_bar   = cb;
            s_in[NF + tid] = h;
            const size_t idx = (bT + t) * HID + tid;
            out_c[idx]  = c;
            out_cb[idx] = cb;
            if (use_ws) h_ws[idx] = h;
        }
        // Prefetch x_{t+1}; consumed at next Phase A (same threads), no hazard.
        if (tid < NF && t + 1 < SEQ)
            xpref = ldin(batch, (bT + t + 1) * CH + 1 + tid, f32);
    }
}

// Intensity head from fp32 h in workspace: softplus(h @ W_int + b_int).
__global__ __launch_bounds__(256) void intensity_ws(
    const float* __restrict__ h_ws, const void* __restrict__ W_int,
    const void* __restrict__ b_int, float* __restrict__ out_int,
    const int* __restrict__ flag)
{
    const bool f32 = flag ? (*flag != 0) : true;
    __shared__ float s_w[HID * NF];
    __shared__ float s_b[NF];
    const int tx = threadIdx.x;          // 0..31 (output feature)
    const int ty = threadIdx.y;          // 0..7  (row within block)
    const int lt = ty * 32 + tx;
    for (int k = lt; k < HID * NF; k += 256) s_w[k] = ldin(W_int, k, f32);
    if (lt < NF) s_b[lt] = ldin(b_int, lt, f32);
    __syncthreads();

    const int b = blockIdx.y;
    const int t = blockIdx.x * 8 + ty;
    if (t >= SEQ - 1) return;
    const float* hr = h_ws + ((size_t)b * SEQ + t) * HID;
    float acc = s_b[tx];
#pragma unroll
    for (int k = 0; k < HID; ++k) acc = fmaf(hr[k], s_w[k * NF + tx], acc);
    out_int[((size_t)b * (SEQ - 1) + t) * NF + tx] = softplus_f(acc);
}

// Fallback (ws too small): recompute h from fp32 outputs (o, c, cbar, delta) + dt.
__global__ __launch_bounds__(256) void intensity_rec(
    const void* __restrict__ batch, const float* __restrict__ out,
    const void* __restrict__ W_int, const void* __restrict__ b_int,
    float* __restrict__ out_int, const int* __restrict__ flag)
{
    const bool f32 = flag ? (*flag != 0) : true;
    __shared__ float s_w[HID * NF];
    __shared__ float s_b[NF];
    __shared__ float s_h[8][HID];
    const int tx = threadIdx.x, ty = threadIdx.y;
    const int lt = ty * 32 + tx;
    for (int k = lt; k < HID * NF; k += 256) s_w[k] = ldin(W_int, k, f32);
    if (lt < NF) s_b[lt] = ldin(b_int, lt, f32);

    const int b  = blockIdx.y;
    const int t0 = blockIdx.x * 8;
    const float* out_o  = out;
    const float* out_c  = out + (size_t)BATCHN * SEQ * HID;
    const float* out_cb = out + 2 * (size_t)BATCHN * SEQ * HID;
    const float* out_dl = out + 3 * (size_t)BATCHN * SEQ * HID;

#pragma unroll
    for (int r = 0; r < 2; ++r) {
        const int flat = lt + r * 256;   // 0..511
        const int row  = flat >> 6;
        const int k    = flat & 63;
        const int t    = t0 + row;
        if (t < SEQ - 1) {
            const size_t idx = ((size_t)b * SEQ + t) * HID + k;
            const float og = out_o[idx];
            const float c  = out_c[idx];
            const float cb = out_cb[idx];
            const float dl = out_dl[idx];
            const float t_a = ldin(batch, ((size_t)b * SEQ + t) * CH, f32);
            const float t_b = ldin(batch, ((size_t)b * SEQ + t + 1) * CH, f32);
            const float dt = fmaxf(t_b - t_a, 0.0f);
            const float cd = cb + (c - cb) * __expf(-dl * dt);
            s_h[row][k] = og * tanh_f(cd);
        }
    }
    __syncthreads();
    const int t = t0 + ty;
    if (t >= SEQ - 1) return;
    float acc = s_b[tx];
#pragma unroll
    for (int k = 0; k < HID; ++k) acc = fmaf(s_h[ty][k], s_w[k * NF + tx], acc);
    out_int[((size_t)b * (SEQ - 1) + t) * NF + tx] = softplus_f(acc);
}

extern "C" void kernel_launch(void* const* d_in, const int* in_sizes, int n_in,
                              void* d_out, int out_size, void* d_ws, size_t ws_size,
                              hipStream_t stream) {
    const void* batch = d_in[0];
    const void* W_rec = d_in[1];
    const void* b_rec = d_in[2];
    const void* W_int = d_in[3];
    const void* b_int = d_in[4];
    float* out = (float*)d_out;

    // ws layout: [0,256) dtype flag; [256, 256+h_bytes) fp32 h buffer.
    const size_t h_bytes = (size_t)BATCHN * SEQ * HID * sizeof(float);
    int* flag = (ws_size >= 4) ? (int*)d_ws : nullptr;
    const int use_ws = (ws_size >= 256 + h_bytes) ? 1 : 0;  // launch-constant
    float* h_ws = (float*)((char*)d_ws + 256);

    if (flag) detect_dtype<<<1, 64, 0, stream>>>(batch, flag);

    ctlstm_rec<<<BATCHN, G7, 0, stream>>>(batch, W_rec, b_rec, out, h_ws, use_ws, flag);

    float* out_int = out + 4 * (size_t)BATCHN * SEQ * HID;
    if (use_ws)
        intensity_ws<<<dim3((SEQ - 1 + 7) / 8, BATCHN), dim3(32, 8), 0, stream>>>(
            h_ws, W_int, b_int, out_int, flag);
    else
        intensity_rec<<<dim3((SEQ - 1 + 7) / 8, BATCHN), dim3(32, 8), 0, stream>>>(
            batch, out, W_int, b_int, out_int, flag);
}

// Round 6
// 1813.603 us; speedup vs baseline: 1.6822x; 1.3200x over previous
//
#include <hip/hip_runtime.h>
#include <hip/hip_bf16.h>

#define BATCHN 64
#define SEQ    2048
#define HID    64
#define NF     32
#define DIN    96      // NF + HID
#define G7     448     // 7 * HID
#define CH     33      // time + 32 marks

using bf16 = __hip_bfloat16;

__device__ __forceinline__ float b2f(bf16 v) { return __bfloat162float(v); }

// Inputs are float32 (verified R4/R5). flag==1 -> fp32, flag==0 -> bf16.
__device__ __forceinline__ float ldin(const void* p, size_t i, bool f32) {
    return f32 ? ((const float*)p)[i] : b2f(((const bf16*)p)[i]);
}

// Fast math: v_exp/v_rcp based, saturation-safe, NaN-free (verified R5).
__device__ __forceinline__ float fast_rcp(float x) { return __builtin_amdgcn_rcpf(x); }
__device__ __forceinline__ float sigmoid_f(float x) {
    return fast_rcp(1.0f + __expf(-x));
}
__device__ __forceinline__ float tanh_f(float x) {
    float e = __expf(2.0f * x);
    return 1.0f - 2.0f * fast_rcp(e + 1.0f);
}
__device__ __forceinline__ float softplus_f(float x) {
    float e = __expf(-fabsf(x));
    return fmaxf(x, 0.0f) + __logf(1.0f + e);
}

__global__ void detect_dtype(const void* batch, int* flag) {
    if (threadIdx.x != 0 || blockIdx.x != 0) return;
    const float* bf = (const float*)batch;
    bool mono = true;
    float prev = bf[0];
    if (!(prev > 0.004f && prev < 1.3f)) mono = false;
    for (int t = 1; t < 16 && mono; ++t) {
        float cur = bf[(size_t)t * CH];
        if (!(cur > prev && (cur - prev) < 1.3f)) mono = false;
        prev = cur;
    }
    *flag = mono ? 1 : 0;
}

// ---------------- x-projection GEMM (fully parallel) ----------------
// xz[row][col] = b_rec[col] + sum_k x[row][k] * W_rec[k][col],  row=(b,t) flat.
__global__ __launch_bounds__(G7) void xproj_gemm(
    const void* __restrict__ batch, const void* __restrict__ W_rec,
    const void* __restrict__ b_rec, float* __restrict__ xz,
    const int* __restrict__ flag)
{
    const bool f32 = *flag != 0;
    const int tid = threadIdx.x;
    const size_t base = (size_t)blockIdx.x * 64;   // 64 rows per block

    // x-part weight column in registers: branch-free unrolled init.
    float wx[NF];
    if (f32) {
        const float* W = (const float*)W_rec;
#pragma unroll
        for (int k = 0; k < NF; ++k) wx[k] = W[(size_t)k * G7 + tid];
    } else {
        const bf16* W = (const bf16*)W_rec;
#pragma unroll
        for (int k = 0; k < NF; ++k) wx[k] = b2f(W[(size_t)k * G7 + tid]);
    }
    const float bias = ldin(b_rec, tid, f32);

    __shared__ __align__(16) float s_x[64][NF];    // 8 KB
    for (int i = tid; i < 64 * NF; i += G7) {
        const int r = i >> 5, k = i & 31;
        s_x[r][k] = ldin(batch, (base + r) * CH + 1 + k, f32);
    }
    __syncthreads();

    for (int r = 0; r < 64; ++r) {
        const float4* xv = (const float4*)s_x[r];
        float a0 = 0.f, a1 = 0.f, a2 = 0.f, a3 = 0.f;
#pragma unroll
        for (int k4 = 0; k4 < NF / 4; ++k4) {
            float4 v = xv[k4];
            a0 = fmaf(v.x, wx[4 * k4 + 0], a0);
            a1 = fmaf(v.y, wx[4 * k4 + 1], a1);
            a2 = fmaf(v.z, wx[4 * k4 + 2], a2);
            a3 = fmaf(v.w, wx[4 * k4 + 3], a3);
        }
        xz[(base + r) * G7 + tid] = bias + ((a0 + a1) + (a2 + a3));
    }
}

// ---------------- recurrent kernel, xz path ----------------
// One block per chain; 448 threads = one per z column. ONE barrier per step:
// s_act double-buffered by parity; s_h is wave-private (Phase C replicated in
// every wave => h write->read is intra-wave, no cross-wave hazard).
__global__ __launch_bounds__(G7, 2) void ctlstm_rec_xz(
    const void* __restrict__ batch, const void* __restrict__ W_rec,
    const float* __restrict__ xz, float* __restrict__ out,
    float* __restrict__ h_ws, const int* __restrict__ flag)
{
    const bool f32 = *flag != 0;
    const int tid  = threadIdx.x;
    const int wave = tid >> 6;      // 0:i 1:f 2:g 3:o 4:ibar 5:fbar 6:delta
    const int lane = tid & 63;
    const int b    = blockIdx.x;
    const size_t bT = (size_t)b * SEQ;

    float* out_o  = out;
    float* out_c  = out + (size_t)BATCHN * SEQ * HID;
    float* out_cb = out + 2 * (size_t)BATCHN * SEQ * HID;
    float* out_dl = out + 3 * (size_t)BATCHN * SEQ * HID;

    __shared__ __align__(16) float s_h[7][HID];    // wave-private h copies
    __shared__ float s_act[2][G7];                 // parity double-buffer
    __shared__ float s_times[SEQ];

    // h-part weight column (64 fp32) in registers: branch-free unrolled init.
    float wh[HID];
    if (f32) {
        const float* W = (const float*)W_rec;
#pragma unroll
        for (int k = 0; k < HID; ++k) wh[k] = W[(size_t)(NF + k) * G7 + tid];
    } else {
        const bf16* W = (const bf16*)W_rec;
#pragma unroll
        for (int k = 0; k < HID; ++k) wh[k] = b2f(W[(size_t)(NF + k) * G7 + tid]);
    }

    for (int i = tid; i < SEQ; i += G7)
        s_times[i] = ldin(batch, (bT + i) * CH, f32);
    s_h[wave][lane] = 0.0f;                        // h0 (wave-private copy)
    float c_decay = 0.0f, c_bar = 0.0f;            // replicated state, j = lane

    float xz_cur = xz[bT * G7 + tid];
    float xz_next = 0.0f;
    __syncthreads();

    for (int t = 0; t < SEQ; ++t) {
        // ---- Phase B: z = xz + dot(h, wh); reads own wave's s_h copy (no barrier)
        const float4* hv = (const float4*)s_h[wave];
        float a0 = 0.f, a1 = 0.f, a2 = 0.f, a3 = 0.f;
#pragma unroll
        for (int k4 = 0; k4 < HID / 4; ++k4) {
            float4 v = hv[k4];
            a0 = fmaf(v.x, wh[4 * k4 + 0], a0);
            a1 = fmaf(v.y, wh[4 * k4 + 1], a1);
            a2 = fmaf(v.z, wh[4 * k4 + 2], a2);
            a3 = fmaf(v.w, wh[4 * k4 + 3], a3);
        }
        const float z = xz_cur + ((a0 + a1) + (a2 + a3));

        float act;
        if (wave == 2)      act = tanh_f(z);
        else if (wave == 6) act = softplus_f(z);
        else                act = sigmoid_f(z);
        s_act[t & 1][tid] = act;
        __syncthreads();   // THE barrier: acts visible; also orders parity reuse

        // Prefetch next xz (consumed next step; a full step of latency cover).
        if (t + 1 < SEQ) xz_next = xz[(bT + t + 1) * G7 + tid];

        // ---- Phase C: replicated in every wave for hidden unit j = lane.
        const float ig = s_act[t & 1][lane];
        const float fg = s_act[t & 1][HID + lane];
        const float gg = s_act[t & 1][2 * HID + lane];
        const float og = s_act[t & 1][3 * HID + lane];
        const float ib = s_act[t & 1][4 * HID + lane];
        const float fb = s_act[t & 1][5 * HID + lane];
        const float dl = s_act[t & 1][6 * HID + lane];
        const float c  = fg * c_decay + ig * gg;
        const float cbn = fb * c_bar + ib * gg;
        float dt = (t + 1 < SEQ) ? (s_times[t + 1] - s_times[t]) : 0.0f;
        dt = fmaxf(dt, 0.0f);
        const float cd = cbn + (c - cbn) * __expf(-dl * dt);
        const float h  = og * tanh_f(cd);
        c_decay = cd;
        c_bar   = cbn;
        s_h[wave][lane] = h;      // own copy; read next step by same wave

        // Global stores AFTER the barrier: drained at next step's barrier (~free).
        const size_t idx = (bT + t) * HID + lane;
        if (wave == 0) out_c[idx]  = c;
        else if (wave == 1) out_cb[idx] = cbn;
        else if (wave == 2) h_ws[idx]   = h;
        else if (wave == 3) out_o[idx]  = act;   // own phase-B act
        else if (wave == 6) out_dl[idx] = act;   // own phase-B act
        xz_cur = xz_next;
    }
}

// ---------------- fallback recurrent kernel (R5 structure, no xz ws) --------
__global__ __launch_bounds__(G7, 2) void ctlstm_rec(
    const void* __restrict__ batch, const void* __restrict__ W_rec,
    const void* __restrict__ b_rec, float* __restrict__ out,
    float* __restrict__ h_ws, int use_ws, const int* __restrict__ flag)
{
    const bool f32 = flag ? (*flag != 0) : true;
    const int tid = threadIdx.x;
    const int b   = blockIdx.x;
    const size_t bT = (size_t)b * SEQ;

    float* out_o  = out;
    float* out_c  = out + (size_t)BATCHN * SEQ * HID;
    float* out_cb = out + 2 * (size_t)BATCHN * SEQ * HID;
    float* out_dl = out + 3 * (size_t)BATCHN * SEQ * HID;

    __shared__ __align__(16) float s_in[DIN];
    __shared__ float s_act[G7];
    __shared__ float s_times[SEQ];

    float wcol[DIN];
    if (f32) {
        const float* W = (const float*)W_rec;
#pragma unroll
        for (int k = 0; k < DIN; ++k) wcol[k] = W[(size_t)k * G7 + tid];
    } else {
        const bf16* W = (const bf16*)W_rec;
#pragma unroll
        for (int k = 0; k < DIN; ++k) wcol[k] = b2f(W[(size_t)k * G7 + tid]);
    }
    const float bias = ldin(b_rec, tid, f32);

    for (int i = tid; i < SEQ; i += G7)
        s_times[i] = ldin(batch, (bT + i) * CH, f32);

    if (tid >= NF && tid < DIN) s_in[tid] = 0.0f;
    float c_decay = 0.0f, c_bar = 0.0f;

    float xpref = 0.0f;
    if (tid < NF) xpref = ldin(batch, bT * CH + 1 + tid, f32);
    __syncthreads();

    const int gate = tid >> 6;
    const int lane = tid & 63;

    for (int t = 0; t < SEQ; ++t) {
        if (tid < NF) s_in[tid] = xpref;
        __syncthreads();

        const float4* sv = (const float4*)s_in;
        float a0 = 0.f, a1 = 0.f, a2 = 0.f, a3 = 0.f;
#pragma unroll
        for (int k4 = 0; k4 < DIN / 4; ++k4) {
            float4 v = sv[k4];
            a0 = fmaf(v.x, wcol[4 * k4 + 0], a0);
            a1 = fmaf(v.y, wcol[4 * k4 + 1], a1);
            a2 = fmaf(v.z, wcol[4 * k4 + 2], a2);
            a3 = fmaf(v.w, wcol[4 * k4 + 3], a3);
        }
        const float z = bias + ((a0 + a1) + (a2 + a3));

        float act;
        if (gate == 2)      act = tanh_f(z);
        else if (gate == 6) act = softplus_f(z);
        else                act = sigmoid_f(z);
        s_act[tid] = act;

        const size_t oidx = (bT + t) * HID + lane;
        if (gate == 3) out_o[oidx]  = act;
        if (gate == 6) out_dl[oidx] = act;
        __syncthreads();

        if (tid < HID) {
            const float ig = s_act[tid];
            const float fg = s_act[HID + tid];
            const float gg = s_act[2 * HID + tid];
            const float og = s_act[3 * HID + tid];
            const float ib = s_act[4 * HID + tid];
            const float fb = s_act[5 * HID + tid];
            const float dl = s_act[6 * HID + tid];
            const float c  = fg * c_decay + ig * gg;
            const float cb = fb * c_bar + ib * gg;
            float dt = (t + 1 < SEQ) ? (s_times[t + 1] - s_times[t]) : 0.0f;
            dt = fmaxf(dt, 0.0f);
            const float cd = cb + (c - cb) * __expf(-dl * dt);
            const float h  = og * tanh_f(cd);
            c_decay = cd;
            c_bar   = cb;
            s_in[NF + tid] = h;
            const size_t idx = (bT + t) * HID + tid;
            out_c[idx]  = c;
            out_cb[idx] = cb;
            if (use_ws) h_ws[idx] = h;
        }
        if (tid < NF && t + 1 < SEQ)
            xpref = ldin(batch, (bT + t + 1) * CH + 1 + tid, f32);
    }
}

// ---------------- intensity head ----------------
__global__ __launch_bounds__(256) void intensity_ws(
    const float* __restrict__ h_ws, const void* __restrict__ W_int,
    const void* __restrict__ b_int, float* __restrict__ out_int,
    const int* __restrict__ flag)
{
    const bool f32 = flag ? (*flag != 0) : true;
    __shared__ float s_w[HID * NF];
    __shared__ float s_b[NF];
    const int tx = threadIdx.x, ty = threadIdx.y;
    const int lt = ty * 32 + tx;
    for (int k = lt; k < HID * NF; k += 256) s_w[k] = ldin(W_int, k, f32);
    if (lt < NF) s_b[lt] = ldin(b_int, lt, f32);
    __syncthreads();

    const int b = blockIdx.y;
    const int t = blockIdx.x * 8 + ty;
    if (t >= SEQ - 1) return;
    const float* hr = h_ws + ((size_t)b * SEQ + t) * HID;
    float acc = s_b[tx];
#pragma unroll
    for (int k = 0; k < HID; ++k) acc = fmaf(hr[k], s_w[k * NF + tx], acc);
    out_int[((size_t)b * (SEQ - 1) + t) * NF + tx] = softplus_f(acc);
}

__global__ __launch_bounds__(256) void intensity_rec(
    const void* __restrict__ batch, const float* __restrict__ out,
    const void* __restrict__ W_int, const void* __restrict__ b_int,
    float* __restrict__ out_int, const int* __restrict__ flag)
{
    const bool f32 = flag ? (*flag != 0) : true;
    __shared__ float s_w[HID * NF];
    __shared__ float s_b[NF];
    __shared__ float s_h[8][HID];
    const int tx = threadIdx.x, ty = threadIdx.y;
    const int lt = ty * 32 + tx;
    for (int k = lt; k < HID * NF; k += 256) s_w[k] = ldin(W_int, k, f32);
    if (lt < NF) s_b[lt] = ldin(b_int, lt, f32);

    const int b  = blockIdx.y;
    const int t0 = blockIdx.x * 8;
    const float* out_o  = out;
    const float* out_c  = out + (size_t)BATCHN * SEQ * HID;
    const float* out_cb = out + 2 * (size_t)BATCHN * SEQ * HID;
    const float* out_dl = out + 3 * (size_t)BATCHN * SEQ * HID;

#pragma unroll
    for (int r = 0; r < 2; ++r) {
        const int flat = lt + r * 256;
        const int row  = flat >> 6;
        const int k    = flat & 63;
        const int t    = t0 + row;
        if (t < SEQ - 1) {
            const size_t idx = ((size_t)b * SEQ + t) * HID + k;
            const float og = out_o[idx];
            const float c  = out_c[idx];
            const float cb = out_cb[idx];
            const float dl = out_dl[idx];
            const float t_a = ldin(batch, ((size_t)b * SEQ + t) * CH, f32);
            const float t_b = ldin(batch, ((size_t)b * SEQ + t + 1) * CH, f32);
            const float dt = fmaxf(t_b - t_a, 0.0f);
            const float cd = cb + (c - cb) * __expf(-dl * dt);
            s_h[row][k] = og * tanh_f(cd);
        }
    }
    __syncthreads();
    const int t = t0 + ty;
    if (t >= SEQ - 1) return;
    float acc = s_b[tx];
#pragma unroll
    for (int k = 0; k < HID; ++k) acc = fmaf(s_h[ty][k], s_w[k * NF + tx], acc);
    out_int[((size_t)b * (SEQ - 1) + t) * NF + tx] = softplus_f(acc);
}

extern "C" void kernel_launch(void* const* d_in, const int* in_sizes, int n_in,
                              void* d_out, int out_size, void* d_ws, size_t ws_size,
                              hipStream_t stream) {
    const void* batch = d_in[0];
    const void* W_rec = d_in[1];
    const void* b_rec = d_in[2];
    const void* W_int = d_in[3];
    const void* b_int = d_in[4];
    float* out = (float*)d_out;

    // ws layout: [0,256) flag | [256, 256+hb) fp32 h | [256+hb, ...) xz buffer
    const size_t hb  = (size_t)BATCHN * SEQ * HID * sizeof(float);   // 33.5 MB
    const size_t xzb = (size_t)BATCHN * SEQ * G7  * sizeof(float);   // 235 MB
    int*   flag = (ws_size >= 4) ? (int*)d_ws : nullptr;
    float* h_ws = (float*)((char*)d_ws + 256);
    float* xz   = (float*)((char*)d_ws + 256 + hb);
    const int have_h  = (ws_size >= 256 + hb) ? 1 : 0;          // launch-constant
    const int have_xz = (ws_size >= 256 + hb + xzb) ? 1 : 0;    // launch-constant

    if (flag) detect_dtype<<<1, 64, 0, stream>>>(batch, flag);

    float* out_int = out + 4 * (size_t)BATCHN * SEQ * HID;

    if (have_xz) {
        xproj_gemm<<<(BATCHN * SEQ) / 64, G7, 0, stream>>>(batch, W_rec, b_rec, xz, flag);
        ctlstm_rec_xz<<<BATCHN, G7, 0, stream>>>(batch, W_rec, xz, out, h_ws, flag);
        intensity_ws<<<dim3((SEQ - 1 + 7) / 8, BATCHN), dim3(32, 8), 0, stream>>>(
            h_ws, W_int, b_int, out_int, flag);
    } else if (have_h) {
        ctlstm_rec<<<BATCHN, G7, 0, stream>>>(batch, W_rec, b_rec, out, h_ws, 1, flag);
        intensity_ws<<<dim3((SEQ - 1 + 7) / 8, BATCHN), dim3(32, 8), 0, stream>>>(
            h_ws, W_int, b_int, out_int, flag);
    } else {
        ctlstm_rec<<<BATCHN, G7, 0, stream>>>(batch, W_rec, b_rec, out, h_ws, 0, flag);
        intensity_rec<<<dim3((SEQ - 1 + 7) / 8, BATCHN), dim3(32, 8), 0, stream>>>(
            batch, out, W_int, b_int, out_int, flag);
    }
}